// Round 1
// baseline (413.407 us; speedup 1.0000x reference)
//
#include <hip/hip_runtime.h>
#include <math.h>

#define BB 8
#define SS 2048
#define HH 1024
#define DD 64

// score = (1 + acos(clip(cos)))^-65.5
__device__ __forceinline__ float score_fn(float cosv) {
    const float lo = -1.0f + 1e-7f;
    const float hi =  1.0f - 1e-7f;
    cosv = fminf(fmaxf(cosv, lo), hi);
    float g = acosf(cosv);
    return exp2f(-65.5f * log2f(1.0f + g));
}

// K1: q,k,v = l2norm(x @ W + b). Block = 256 threads, 16 rows. Grid = B*S/16.
__global__ __launch_bounds__(256) void k_proj(
    const float* __restrict__ x,
    const float* __restrict__ Wq, const float* __restrict__ bq,
    const float* __restrict__ Wk, const float* __restrict__ bk,
    const float* __restrict__ Wv, const float* __restrict__ bv,
    float* __restrict__ qo, float* __restrict__ ko, float* __restrict__ vo)
{
    __shared__ float xs[16][64];    // 4 KB
    __shared__ float wl[64][192];   // 48 KB: [j][mat*64+d]
    const int t = threadIdx.x;
    const int row0 = blockIdx.x * 16;
    const int lane = t & 63;
    const int wave = t >> 6;   // 0..3, wave w owns rows 4w..4w+3

    float acc[4][3];
    #pragma unroll
    for (int i = 0; i < 4; ++i)
        for (int m = 0; m < 3; ++m) acc[i][m] = 0.0f;

    for (int ch = 0; ch < 16; ++ch) {
        const int j0 = ch * 64;
        // stage x chunk: thread -> (row = t>>4, j4 = t&15)
        {
            int r = t >> 4, j4 = t & 15;
            float4 xv = *(const float4*)&x[(size_t)(row0 + r) * HH + j0 + j4 * 4];
            *(float4*)&xs[r][j4 * 4] = xv;
        }
        // stage W chunk [64][192]
        {
            auto loadW = [&](const float* __restrict__ W, int m) {
                #pragma unroll
                for (int i = 0; i < 4; ++i) {
                    int idx = t + i * 256;          // 0..1023
                    int jr = idx >> 4, dq = idx & 15;
                    float4 w4 = *(const float4*)&W[(size_t)(j0 + jr) * DD + dq * 4];
                    *(float4*)&wl[jr][m * 64 + dq * 4] = w4;
                }
            };
            loadW(Wq, 0); loadW(Wk, 1); loadW(Wv, 2);
        }
        __syncthreads();
        #pragma unroll 4
        for (int j = 0; j < 64; ++j) {
            float w0 = wl[j][lane];
            float w1 = wl[j][64 + lane];
            float w2 = wl[j][128 + lane];
            float x0 = xs[(wave << 2) + 0][j];
            float x1 = xs[(wave << 2) + 1][j];
            float x2 = xs[(wave << 2) + 2][j];
            float x3 = xs[(wave << 2) + 3][j];
            acc[0][0] = fmaf(x0, w0, acc[0][0]); acc[0][1] = fmaf(x0, w1, acc[0][1]); acc[0][2] = fmaf(x0, w2, acc[0][2]);
            acc[1][0] = fmaf(x1, w0, acc[1][0]); acc[1][1] = fmaf(x1, w1, acc[1][1]); acc[1][2] = fmaf(x1, w2, acc[1][2]);
            acc[2][0] = fmaf(x2, w0, acc[2][0]); acc[2][1] = fmaf(x2, w1, acc[2][1]); acc[2][2] = fmaf(x2, w2, acc[2][2]);
            acc[3][0] = fmaf(x3, w0, acc[3][0]); acc[3][1] = fmaf(x3, w1, acc[3][1]); acc[3][2] = fmaf(x3, w2, acc[3][2]);
        }
        __syncthreads();
    }
    float b0 = bq[lane], b1 = bk[lane], b2 = bv[lane];
    #pragma unroll
    for (int i = 0; i < 4; ++i) {
        int row = row0 + (wave << 2) + i;
        float v0 = acc[i][0] + b0;
        float v1 = acc[i][1] + b1;
        float v2 = acc[i][2] + b2;
        float n0 = v0 * v0, n1 = v1 * v1, n2 = v2 * v2;
        #pragma unroll
        for (int m = 1; m < 64; m <<= 1) {
            n0 += __shfl_xor(n0, m, 64);
            n1 += __shfl_xor(n1, m, 64);
            n2 += __shfl_xor(n2, m, 64);
        }
        qo[(size_t)row * DD + lane] = v0 / fmaxf(sqrtf(n0), 1e-12f);
        ko[(size_t)row * DD + lane] = v1 / fmaxf(sqrtf(n1), 1e-12f);
        vo[(size_t)row * DD + lane] = v2 / fmaxf(sqrtf(n2), 1e-12f);
    }
}

// K2: score tiles -> scr (probs region of d_out), colsum atomics.
// Grid = 8 b * 16 ktile(128) * 8 qsplit(256) = 1024. Block 256.
__global__ __launch_bounds__(256) void k_score(
    const float* __restrict__ qi, const float* __restrict__ ki,
    float* __restrict__ scr, float* __restrict__ colsum)
{
    __shared__ float kst[64][128];  // 32 KB, transposed [j][k]
    __shared__ float qs[32][64];    // 8 KB
    const int t = threadIdx.x;
    const int bid = blockIdx.x;
    const int b   = bid >> 7;
    const int kt  = (bid & 127) >> 3;
    const int qsp = bid & 7;
    const int k0 = kt * 128;
    const int q0 = qsp * 256;

    // stage k tile transposed
    {
        int kk = t & 127, half = t >> 7;
        #pragma unroll
        for (int i = 0; i < 8; ++i) {
            int j4 = half * 8 + i;
            float4 kv = *(const float4*)&ki[(size_t)(b * SS + k0 + kk) * DD + j4 * 4];
            kst[j4 * 4 + 0][kk] = kv.x;
            kst[j4 * 4 + 1][kk] = kv.y;
            kst[j4 * 4 + 2][kk] = kv.z;
            kst[j4 * 4 + 3][kk] = kv.w;
        }
    }
    const int tk = t & 31;   // 4 keys: k0 + tk*4 + 0..3
    const int tq = t >> 5;   // 0..7 : 4 q rows each
    float cs0 = 0.f, cs1 = 0.f, cs2 = 0.f, cs3 = 0.f;

    for (int it = 0; it < 8; ++it) {
        const int qb = q0 + it * 32;
        __syncthreads();   // protect qs (and first-iter kst)
        #pragma unroll
        for (int i = 0; i < 2; ++i) {
            int idx = t + i * 256;
            int qr = idx >> 4, j4 = idx & 15;
            float4 qv = *(const float4*)&qi[(size_t)(b * SS + qb + qr) * DD + j4 * 4];
            *(float4*)&qs[qr][j4 * 4] = qv;
        }
        __syncthreads();
        float4 acc[4];
        #pragma unroll
        for (int q = 0; q < 4; ++q) acc[q] = make_float4(0.f, 0.f, 0.f, 0.f);
        #pragma unroll 8
        for (int j = 0; j < 64; ++j) {
            float4 kv = *(const float4*)&kst[j][tk * 4];
            #pragma unroll
            for (int q = 0; q < 4; ++q) {
                float qv = qs[tq * 4 + q][j];
                acc[q].x = fmaf(qv, kv.x, acc[q].x);
                acc[q].y = fmaf(qv, kv.y, acc[q].y);
                acc[q].z = fmaf(qv, kv.z, acc[q].z);
                acc[q].w = fmaf(qv, kv.w, acc[q].w);
            }
        }
        #pragma unroll
        for (int q = 0; q < 4; ++q) {
            int qrow = qb + tq * 4 + q;
            float4 s;
            s.x = score_fn(acc[q].x);
            s.y = score_fn(acc[q].y);
            s.z = score_fn(acc[q].z);
            s.w = score_fn(acc[q].w);
            cs0 += s.x; cs1 += s.y; cs2 += s.z; cs3 += s.w;
            *(float4*)&scr[(size_t)(b * SS + qrow) * SS + k0 + tk * 4] = s;
        }
    }
    atomicAdd(&colsum[b * SS + k0 + tk * 4 + 0], cs0);
    atomicAdd(&colsum[b * SS + k0 + tk * 4 + 1], cs1);
    atomicAdd(&colsum[b * SS + k0 + tk * 4 + 2], cs2);
    atomicAdd(&colsum[b * SS + k0 + tk * 4 + 3], cs3);
}

// K3: c = colsum^-0.5
__global__ void k_csc(const float* __restrict__ colsum, float* __restrict__ c) {
    int i = blockIdx.x * 256 + threadIdx.x;
    if (i < BB * SS) c[i] = 1.0f / sqrtf(colsum[i]);
}

// K4: D[q] = sum_k score*c ; out = (score @ (c*v)) / D. Grid = 8 b * 64 qtile(32).
__global__ __launch_bounds__(256) void k_dn(
    const float* __restrict__ scr, const float* __restrict__ vv,
    const float* __restrict__ c, float* __restrict__ Dws, float* __restrict__ out)
{
    __shared__ float vc[128][64];   // 32 KB : v*c chunk
    __shared__ float sc[32][128];   // 16 KB : score chunk
    const int t = threadIdx.x;
    const int b  = blockIdx.x >> 6;
    const int q0 = (blockIdx.x & 63) * 32;
    const int td = t & 63;
    const int tq = t >> 6;   // 0..3 -> 8 q rows each
    float accN[8], accD[8];
    #pragma unroll
    for (int q = 0; q < 8; ++q) { accN[q] = 0.f; accD[q] = 0.f; }

    for (int kc = 0; kc < 16; ++kc) {
        const int k0 = kc * 128;
        __syncthreads();
        #pragma unroll
        for (int i = 0; i < 8; ++i) {
            int idx = t + i * 256;
            int kr = idx >> 4, df = idx & 15;
            float cval = c[b * SS + k0 + kr];
            float4 v4 = *(const float4*)&vv[(size_t)(b * SS + k0 + kr) * DD + df * 4];
            v4.x *= cval; v4.y *= cval; v4.z *= cval; v4.w *= cval;
            *(float4*)&vc[kr][df * 4] = v4;
        }
        #pragma unroll
        for (int i = 0; i < 4; ++i) {
            int idx = t + i * 256;
            int qr = idx >> 5, kf = idx & 31;
            float4 s4 = *(const float4*)&scr[(size_t)(b * SS + q0 + qr) * SS + k0 + kf * 4];
            *(float4*)&sc[qr][kf * 4] = s4;
        }
        __syncthreads();
        #pragma unroll 4
        for (int k = 0; k < 128; ++k) {
            float kvv = vc[k][td];
            #pragma unroll
            for (int q = 0; q < 8; ++q)
                accN[q] = fmaf(sc[tq * 8 + q][k], kvv, accN[q]);
        }
        // D partials: lane td handles k = td and td+64 of this chunk
        float c0 = c[b * SS + k0 + td];
        float c1 = c[b * SS + k0 + 64 + td];
        #pragma unroll
        for (int q = 0; q < 8; ++q) {
            accD[q] = fmaf(sc[tq * 8 + q][td], c0, accD[q]);
            accD[q] = fmaf(sc[tq * 8 + q][64 + td], c1, accD[q]);
        }
    }
    #pragma unroll
    for (int q = 0; q < 8; ++q) {
        #pragma unroll
        for (int m = 1; m < 64; m <<= 1)
            accD[q] += __shfl_xor(accD[q], m, 64);
    }
    #pragma unroll
    for (int q = 0; q < 8; ++q) {
        int qrow = q0 + tq * 8 + q;
        if (td == 0) Dws[b * SS + qrow] = accD[q];
        out[(size_t)(b * SS + qrow) * DD + td] = accN[q] / accD[q];
    }
}

// K5: probs = score * c[k] / D[q], in place. float4 grid-stride.
__global__ void k_probs(float* __restrict__ scr, const float* __restrict__ c,
                        const float* __restrict__ Dws)
{
    const size_t nf4 = (size_t)BB * SS * SS / 4;
    const size_t stride = (size_t)gridDim.x * blockDim.x;
    for (size_t i = (size_t)blockIdx.x * blockDim.x + threadIdx.x; i < nf4; i += stride) {
        size_t g = i * 4;
        int b   = (int)(g >> 22);
        int rem = (int)(g & ((1u << 22) - 1));
        int row = rem >> 11;
        int kc  = rem & 2047;
        float4 s = ((float4*)scr)[i];
        float4 cc = *(const float4*)&c[b * SS + kc];
        float inv = 1.0f / Dws[b * SS + row];
        s.x *= cc.x * inv;
        s.y *= cc.y * inv;
        s.z *= cc.z * inv;
        s.w *= cc.w * inv;
        ((float4*)scr)[i] = s;
    }
}

extern "C" void kernel_launch(void* const* d_in, const int* in_sizes, int n_in,
                              void* d_out, int out_size, void* d_ws, size_t ws_size,
                              hipStream_t stream)
{
    const float* x  = (const float*)d_in[0];
    const float* Wq = (const float*)d_in[1];
    const float* bq = (const float*)d_in[2];
    const float* Wk = (const float*)d_in[3];
    const float* bk = (const float*)d_in[4];
    const float* Wv = (const float*)d_in[5];
    const float* bv = (const float*)d_in[6];

    float* out   = (float*)d_out;                       // [8,2048,64]
    float* probs = out + (size_t)BB * SS * DD;          // [8,2048,2048] (also score scratch)

    float* ws     = (float*)d_ws;                       // needs ~12.8 MB
    float* qw     = ws;
    float* kw     = qw + (size_t)BB * SS * DD;
    float* vw     = kw + (size_t)BB * SS * DD;
    float* colsum = vw + (size_t)BB * SS * DD;
    float* cw     = colsum + BB * SS;
    float* Dw     = cw + BB * SS;

    hipMemsetAsync(colsum, 0, BB * SS * sizeof(float), stream);
    k_proj <<<BB * SS / 16, 256, 0, stream>>>(x, Wq, bq, Wk, bk, Wv, bv, qw, kw, vw);
    k_score<<<1024, 256, 0, stream>>>(qw, kw, probs, colsum);
    k_csc  <<<BB * SS / 256, 256, 0, stream>>>(colsum, cw);
    k_dn   <<<512, 256, 0, stream>>>(probs, vw, cw, Dw, out);
    k_probs<<<2048, 256, 0, stream>>>(probs, cw, Dw);
}

// Round 2
// 326.867 us; speedup vs baseline: 1.2648x; 1.2648x over previous
//
#include <hip/hip_runtime.h>
#include <math.h>

#define BB 8
#define SS 2048
#define HH 1024
#define DD 64

typedef __attribute__((ext_vector_type(8))) short bf16x8;
typedef __attribute__((ext_vector_type(4))) float f32x4;

__device__ __forceinline__ ushort bf16rne(float f) {
    uint u = __float_as_uint(f);
    uint r = (u + 0x7FFFu + ((u >> 16) & 1u)) >> 16;
    return (ushort)r;
}

// score = (1 + acos(clip(cos)))^-65.5
__device__ __forceinline__ float score_fn(float cosv) {
    const float lo = -1.0f + 1e-7f;
    const float hi =  1.0f - 1e-7f;
    cosv = fminf(fmaxf(cosv, lo), hi);
    float g = acosf(cosv);
    return exp2f(-65.5f * log2f(1.0f + g));
}

// K0: split W into bf16 hi/lo, layout Wcat[n][j], n = mat*64+d. Also bcat.
__global__ __launch_bounds__(256) void k_prep(
    const float* __restrict__ Wq, const float* __restrict__ Wk, const float* __restrict__ Wv,
    const float* __restrict__ bq, const float* __restrict__ bk, const float* __restrict__ bv,
    ushort* __restrict__ Whi, ushort* __restrict__ Wlo, float* __restrict__ bcat)
{
    const int n = blockIdx.x;          // 0..191
    const int m = n >> 6, d = n & 63;
    const float* W = (m == 0) ? Wq : (m == 1 ? Wk : Wv);
    #pragma unroll
    for (int i = 0; i < 4; ++i) {
        int j = i * 256 + threadIdx.x;
        float f = W[(size_t)j * DD + d];
        ushort h = bf16rne(f);
        float hf = __uint_as_float(((uint)h) << 16);
        Whi[(size_t)n * HH + j] = h;
        Wlo[(size_t)n * HH + j] = bf16rne(f - hf);
    }
    if (n == 0 && threadIdx.x < 192) {
        int t = threadIdx.x, mm = t >> 6, dd = t & 63;
        const float* b = (mm == 0) ? bq : (mm == 1 ? bk : bv);
        bcat[t] = b[dd];
    }
}

// K1: q,k,v = l2norm(x @ W + b) via split-bf16 MFMA.
// Grid = 16384/32 = 512 blocks, 256 threads (4 waves). Wave w owns cols 48w..48w+47.
__global__ __launch_bounds__(256) void k_projmm(
    const float* __restrict__ x, const ushort* __restrict__ Whi,
    const ushort* __restrict__ Wlo, const float* __restrict__ bcat,
    float* __restrict__ qo, float* __restrict__ ko, float* __restrict__ vo)
{
    __shared__ __align__(16) char smem[32 * 193 * 4];   // 24.7 KB (xhi/xlo then ctile)
    __shared__ float rns[96];
    __shared__ float bsh[192];
    ushort* xhi = (ushort*)smem;                 // [32][128] bf16, XOR-swizzled 16B units
    ushort* xlo = xhi + 32 * 128;
    float* ctile = (float*)smem;                 // [32][193] epilogue (aliases xhi/xlo)

    const int t = threadIdx.x;
    const int lane = t & 63;
    const int wid = t >> 6;
    const int row0 = blockIdx.x * 32;
    if (t < 192) bsh[t] = bcat[t];

    f32x4 acc[2][3];
    #pragma unroll
    for (int ar = 0; ar < 2; ++ar)
        #pragma unroll
        for (int bc = 0; bc < 3; ++bc)
            acc[ar][bc] = (f32x4){0.f, 0.f, 0.f, 0.f};

    for (int ch = 0; ch < 8; ++ch) {
        const int j0 = ch * 128;
        __syncthreads();
        // stage-convert x chunk [32][128] f32 -> hi/lo bf16 (swizzled 16B units)
        #pragma unroll
        for (int i = 0; i < 2; ++i) {
            int u = i * 256 + t;                 // 0..511
            int row = u >> 4, uc = u & 15;
            const float* xp = &x[(size_t)(row0 + row) * HH + j0 + uc * 8];
            float4 a = *(const float4*)xp;
            float4 b = *(const float4*)(xp + 4);
            float fs[8] = {a.x, a.y, a.z, a.w, b.x, b.y, b.z, b.w};
            bf16x8 hv, lv;
            #pragma unroll
            for (int e = 0; e < 8; ++e) {
                ushort h = bf16rne(fs[e]);
                float hf = __uint_as_float(((uint)h) << 16);
                hv[e] = (short)h;
                lv[e] = (short)bf16rne(fs[e] - hf);
            }
            int su = uc ^ (row & 7);
            *(bf16x8*)(xhi + row * 128 + su * 8) = hv;
            *(bf16x8*)(xlo + row * 128 + su * 8) = lv;
        }
        __syncthreads();
        #pragma unroll
        for (int ks = 0; ks < 4; ++ks) {
            bf16x8 ah[2], al[2], bh[3], bl[3];
            #pragma unroll
            for (int ar = 0; ar < 2; ++ar) {
                int row = ar * 16 + (lane & 15);
                int su = (ks * 4 + (lane >> 4)) ^ (row & 7);
                ah[ar] = *(const bf16x8*)(xhi + row * 128 + su * 8);
                al[ar] = *(const bf16x8*)(xlo + row * 128 + su * 8);
            }
            const int koff = j0 + ks * 32 + (lane >> 4) * 8;
            #pragma unroll
            for (int bc = 0; bc < 3; ++bc) {
                int n = wid * 48 + bc * 16 + (lane & 15);
                bh[bc] = *(const bf16x8*)(Whi + (size_t)n * HH + koff);
                bl[bc] = *(const bf16x8*)(Wlo + (size_t)n * HH + koff);
            }
            #pragma unroll
            for (int ar = 0; ar < 2; ++ar)
                #pragma unroll
                for (int bc = 0; bc < 3; ++bc) {
                    acc[ar][bc] = __builtin_amdgcn_mfma_f32_16x16x32_bf16(ah[ar], bh[bc], acc[ar][bc], 0, 0, 0);
                    acc[ar][bc] = __builtin_amdgcn_mfma_f32_16x16x32_bf16(ah[ar], bl[bc], acc[ar][bc], 0, 0, 0);
                    acc[ar][bc] = __builtin_amdgcn_mfma_f32_16x16x32_bf16(al[ar], bh[bc], acc[ar][bc], 0, 0, 0);
                }
        }
    }
    __syncthreads();
    // dump accs to ctile[row][n]
    #pragma unroll
    for (int ar = 0; ar < 2; ++ar)
        #pragma unroll
        for (int bc = 0; bc < 3; ++bc) {
            int n = wid * 48 + bc * 16 + (lane & 15);
            #pragma unroll
            for (int r = 0; r < 4; ++r) {
                int row = ar * 16 + (lane >> 4) * 4 + r;
                ctile[row * 193 + n] = acc[ar][bc][r];
            }
        }
    __syncthreads();
    if (t < 96) {
        int mat = t >> 5, row = t & 31;
        float ss = 0.f;
        #pragma unroll 8
        for (int d = 0; d < 64; ++d) {
            float v = ctile[row * 193 + mat * 64 + d] + bsh[mat * 64 + d];
            ss = fmaf(v, v, ss);
        }
        rns[t] = 1.0f / fmaxf(sqrtf(ss), 1e-12f);
    }
    __syncthreads();
    #pragma unroll
    for (int i = 0; i < 24; ++i) {
        int idx = i * 256 + t;                  // 0..6143
        int row = idx / 192;
        int n = idx - row * 192;
        float v = (ctile[row * 193 + n] + bsh[n]) * rns[(n >> 6) * 32 + row];
        float* o = (n < 64) ? qo : (n < 128 ? ko : vo);
        o[(size_t)(row0 + row) * DD + (n & 63)] = v;
    }
}

// K2: score tiles -> scr (probs region of d_out), colsum atomics.
__global__ __launch_bounds__(256) void k_score(
    const float* __restrict__ qi, const float* __restrict__ ki,
    float* __restrict__ scr, float* __restrict__ colsum)
{
    __shared__ float kst[64][128];  // 32 KB, transposed [j][k]
    __shared__ float qs[32][64];    // 8 KB
    const int t = threadIdx.x;
    const int bid = blockIdx.x;
    const int b   = bid >> 7;
    const int kt  = (bid & 127) >> 3;
    const int qsp = bid & 7;
    const int k0 = kt * 128;
    const int q0 = qsp * 256;

    {
        int kk = t & 127, half = t >> 7;
        #pragma unroll
        for (int i = 0; i < 8; ++i) {
            int j4 = half * 8 + i;
            float4 kv = *(const float4*)&ki[(size_t)(b * SS + k0 + kk) * DD + j4 * 4];
            kst[j4 * 4 + 0][kk] = kv.x;
            kst[j4 * 4 + 1][kk] = kv.y;
            kst[j4 * 4 + 2][kk] = kv.z;
            kst[j4 * 4 + 3][kk] = kv.w;
        }
    }
    const int tk = t & 31;
    const int tq = t >> 5;
    float cs0 = 0.f, cs1 = 0.f, cs2 = 0.f, cs3 = 0.f;

    for (int it = 0; it < 8; ++it) {
        const int qb = q0 + it * 32;
        __syncthreads();
        #pragma unroll
        for (int i = 0; i < 2; ++i) {
            int idx = t + i * 256;
            int qr = idx >> 4, j4 = idx & 15;
            float4 qv = *(const float4*)&qi[(size_t)(b * SS + qb + qr) * DD + j4 * 4];
            *(float4*)&qs[qr][j4 * 4] = qv;
        }
        __syncthreads();
        float4 acc[4];
        #pragma unroll
        for (int q = 0; q < 4; ++q) acc[q] = make_float4(0.f, 0.f, 0.f, 0.f);
        #pragma unroll 8
        for (int j = 0; j < 64; ++j) {
            float4 kv = *(const float4*)&kst[j][tk * 4];
            #pragma unroll
            for (int q = 0; q < 4; ++q) {
                float qv = qs[tq * 4 + q][j];
                acc[q].x = fmaf(qv, kv.x, acc[q].x);
                acc[q].y = fmaf(qv, kv.y, acc[q].y);
                acc[q].z = fmaf(qv, kv.z, acc[q].z);
                acc[q].w = fmaf(qv, kv.w, acc[q].w);
            }
        }
        #pragma unroll
        for (int q = 0; q < 4; ++q) {
            int qrow = qb + tq * 4 + q;
            float4 s;
            s.x = score_fn(acc[q].x);
            s.y = score_fn(acc[q].y);
            s.z = score_fn(acc[q].z);
            s.w = score_fn(acc[q].w);
            cs0 += s.x; cs1 += s.y; cs2 += s.z; cs3 += s.w;
            *(float4*)&scr[(size_t)(b * SS + qrow) * SS + k0 + tk * 4] = s;
        }
    }
    atomicAdd(&colsum[b * SS + k0 + tk * 4 + 0], cs0);
    atomicAdd(&colsum[b * SS + k0 + tk * 4 + 1], cs1);
    atomicAdd(&colsum[b * SS + k0 + tk * 4 + 2], cs2);
    atomicAdd(&colsum[b * SS + k0 + tk * 4 + 3], cs3);
}

// K3: c = colsum^-0.5
__global__ void k_csc(const float* __restrict__ colsum, float* __restrict__ c) {
    int i = blockIdx.x * 256 + threadIdx.x;
    if (i < BB * SS) c[i] = 1.0f / sqrtf(colsum[i]);
}

// K4: D[q] = sum_k score*c ; out = (score @ (c*v)) / D.
__global__ __launch_bounds__(256) void k_dn(
    const float* __restrict__ scr, const float* __restrict__ vv,
    const float* __restrict__ c, float* __restrict__ Dws, float* __restrict__ out)
{
    __shared__ float vc[128][64];
    __shared__ float sc[32][128];
    const int t = threadIdx.x;
    const int b  = blockIdx.x >> 6;
    const int q0 = (blockIdx.x & 63) * 32;
    const int td = t & 63;
    const int tq = t >> 6;
    float accN[8], accD[8];
    #pragma unroll
    for (int q = 0; q < 8; ++q) { accN[q] = 0.f; accD[q] = 0.f; }

    for (int kc = 0; kc < 16; ++kc) {
        const int k0 = kc * 128;
        __syncthreads();
        #pragma unroll
        for (int i = 0; i < 8; ++i) {
            int idx = t + i * 256;
            int kr = idx >> 4, df = idx & 15;
            float cval = c[b * SS + k0 + kr];
            float4 v4 = *(const float4*)&vv[(size_t)(b * SS + k0 + kr) * DD + df * 4];
            v4.x *= cval; v4.y *= cval; v4.z *= cval; v4.w *= cval;
            *(float4*)&vc[kr][df * 4] = v4;
        }
        #pragma unroll
        for (int i = 0; i < 4; ++i) {
            int idx = t + i * 256;
            int qr = idx >> 5, kf = idx & 31;
            float4 s4 = *(const float4*)&scr[(size_t)(b * SS + q0 + qr) * SS + k0 + kf * 4];
            *(float4*)&sc[qr][kf * 4] = s4;
        }
        __syncthreads();
        #pragma unroll 4
        for (int k = 0; k < 128; ++k) {
            float kvv = vc[k][td];
            #pragma unroll
            for (int q = 0; q < 8; ++q)
                accN[q] = fmaf(sc[tq * 8 + q][k], kvv, accN[q]);
        }
        float c0 = c[b * SS + k0 + td];
        float c1 = c[b * SS + k0 + 64 + td];
        #pragma unroll
        for (int q = 0; q < 8; ++q) {
            accD[q] = fmaf(sc[tq * 8 + q][td], c0, accD[q]);
            accD[q] = fmaf(sc[tq * 8 + q][64 + td], c1, accD[q]);
        }
    }
    #pragma unroll
    for (int q = 0; q < 8; ++q) {
        #pragma unroll
        for (int m = 1; m < 64; m <<= 1)
            accD[q] += __shfl_xor(accD[q], m, 64);
    }
    #pragma unroll
    for (int q = 0; q < 8; ++q) {
        int qrow = q0 + tq * 8 + q;
        if (td == 0) Dws[b * SS + qrow] = accD[q];
        out[(size_t)(b * SS + qrow) * DD + td] = accN[q] / accD[q];
    }
}

// K5: probs = score * c[k] / D[q], in place.
__global__ void k_probs(float* __restrict__ scr, const float* __restrict__ c,
                        const float* __restrict__ Dws)
{
    const size_t nf4 = (size_t)BB * SS * SS / 4;
    const size_t stride = (size_t)gridDim.x * blockDim.x;
    for (size_t i = (size_t)blockIdx.x * blockDim.x + threadIdx.x; i < nf4; i += stride) {
        size_t g = i * 4;
        int b   = (int)(g >> 22);
        int rem = (int)(g & ((1u << 22) - 1));
        int row = rem >> 11;
        int kc  = rem & 2047;
        float4 s = ((float4*)scr)[i];
        float4 cc = *(const float4*)&c[b * SS + kc];
        float inv = 1.0f / Dws[b * SS + row];
        s.x *= cc.x * inv;
        s.y *= cc.y * inv;
        s.z *= cc.z * inv;
        s.w *= cc.w * inv;
        ((float4*)scr)[i] = s;
    }
}

extern "C" void kernel_launch(void* const* d_in, const int* in_sizes, int n_in,
                              void* d_out, int out_size, void* d_ws, size_t ws_size,
                              hipStream_t stream)
{
    const float* x  = (const float*)d_in[0];
    const float* Wq = (const float*)d_in[1];
    const float* bq = (const float*)d_in[2];
    const float* Wk = (const float*)d_in[3];
    const float* bk = (const float*)d_in[4];
    const float* Wv = (const float*)d_in[5];
    const float* bv = (const float*)d_in[6];

    float* out   = (float*)d_out;                       // [8,2048,64]
    float* probs = out + (size_t)BB * SS * DD;          // [8,2048,2048] (score scratch)

    float* ws     = (float*)d_ws;
    const size_t NQ = (size_t)BB * SS * DD;
    float* qw     = ws;
    float* kw     = qw + NQ;
    float* vw     = kw + NQ;
    float* colsum = vw + NQ;
    float* cw     = colsum + BB * SS;
    float* Dw     = cw + BB * SS;
    float* bcat   = Dw + BB * SS;
    ushort* Whi   = (ushort*)(bcat + 192);
    ushort* Wlo   = Whi + (size_t)192 * HH;

    hipMemsetAsync(colsum, 0, BB * SS * sizeof(float), stream);
    k_prep  <<<192, 256, 0, stream>>>(Wq, Wk, Wv, bq, bk, bv, Whi, Wlo, bcat);
    k_projmm<<<512, 256, 0, stream>>>(x, Whi, Wlo, bcat, qw, kw, vw);
    k_score <<<1024, 256, 0, stream>>>(qw, kw, probs, colsum);
    k_csc   <<<BB * SS / 256, 256, 0, stream>>>(colsum, cw);
    k_dn    <<<512, 256, 0, stream>>>(probs, vw, cw, Dw, out);
    k_probs <<<2048, 256, 0, stream>>>(probs, cw, Dw);
}

// Round 3
// 251.100 us; speedup vs baseline: 1.6464x; 1.3017x over previous
//
#include <hip/hip_runtime.h>
#include <math.h>

#define BB 8
#define SS 2048
#define HH 1024
#define DD 64
#define NCV 65

typedef __attribute__((ext_vector_type(8))) short bf16x8;
typedef __attribute__((ext_vector_type(4))) float f32x4;

#define MFMA16(a, b, c) __builtin_amdgcn_mfma_f32_16x16x32_bf16(a, b, c, 0, 0, 0)

__device__ __forceinline__ ushort bf16rne(float f) {
    uint u = __float_as_uint(f);
    uint r = (u + 0x7FFFu + ((u >> 16) & 1u)) >> 16;
    return (ushort)r;
}
__device__ __forceinline__ float bf2f(ushort h) {
    return __uint_as_float(((uint)h) << 16);
}

// score = (1 + acos(clip(cos)))^-65.5
__device__ __forceinline__ float score_fn(float cosv) {
    const float lo = -1.0f + 1e-7f;
    const float hi =  1.0f - 1e-7f;
    cosv = fminf(fmaxf(cosv, lo), hi);
    float g = acosf(cosv);
    return exp2f(-65.5f * log2f(1.0f + g));
}

// K0: split W into bf16 hi/lo, layout Wcat[n][j], n = mat*64+d. Also bcat.
__global__ __launch_bounds__(256) void k_prep(
    const float* __restrict__ Wq, const float* __restrict__ Wk, const float* __restrict__ Wv,
    const float* __restrict__ bq, const float* __restrict__ bk, const float* __restrict__ bv,
    ushort* __restrict__ Whi, ushort* __restrict__ Wlo, float* __restrict__ bcat)
{
    const int n = blockIdx.x;          // 0..191
    const int m = n >> 6, d = n & 63;
    const float* W = (m == 0) ? Wq : (m == 1 ? Wk : Wv);
    #pragma unroll
    for (int i = 0; i < 4; ++i) {
        int j = i * 256 + threadIdx.x;
        float f = W[(size_t)j * DD + d];
        ushort h = bf16rne(f);
        Whi[(size_t)n * HH + j] = h;
        Wlo[(size_t)n * HH + j] = bf16rne(f - bf2f(h));
    }
    if (n == 0 && threadIdx.x < 192) {
        int t = threadIdx.x, mm = t >> 6, dd = t & 63;
        const float* b = (mm == 0) ? bq : (mm == 1 ? bk : bv);
        bcat[t] = b[dd];
    }
}

// K1: q,k,v = l2norm(x @ W + b) via split-bf16 MFMA.
// q,k emitted as split hi/lo bf16 (for downstream MFMA); v as f32.
__global__ __launch_bounds__(256) void k_projmm(
    const float* __restrict__ x, const ushort* __restrict__ Whi,
    const ushort* __restrict__ Wlo, const float* __restrict__ bcat,
    ushort* __restrict__ qh, ushort* __restrict__ ql,
    ushort* __restrict__ kh, ushort* __restrict__ kl,
    float* __restrict__ vw)
{
    __shared__ __align__(16) char smem[32 * 193 * 4];
    __shared__ float rns[96];
    __shared__ float bsh[192];
    ushort* xhi = (ushort*)smem;                 // [32][128] bf16, XOR-swizzled 16B units
    ushort* xlo = xhi + 32 * 128;
    float* ctile = (float*)smem;                 // [32][193] epilogue (aliases xhi/xlo)

    const int t = threadIdx.x;
    const int lane = t & 63;
    const int wid = t >> 6;
    const int row0 = blockIdx.x * 32;
    if (t < 192) bsh[t] = bcat[t];

    f32x4 acc[2][3];
    #pragma unroll
    for (int ar = 0; ar < 2; ++ar)
        #pragma unroll
        for (int bc = 0; bc < 3; ++bc)
            acc[ar][bc] = (f32x4){0.f, 0.f, 0.f, 0.f};

    for (int ch = 0; ch < 8; ++ch) {
        const int j0 = ch * 128;
        __syncthreads();
        #pragma unroll
        for (int i = 0; i < 2; ++i) {
            int u = i * 256 + t;
            int row = u >> 4, uc = u & 15;
            const float* xp = &x[(size_t)(row0 + row) * HH + j0 + uc * 8];
            float4 a = *(const float4*)xp;
            float4 b = *(const float4*)(xp + 4);
            float fs[8] = {a.x, a.y, a.z, a.w, b.x, b.y, b.z, b.w};
            bf16x8 hv, lv;
            #pragma unroll
            for (int e = 0; e < 8; ++e) {
                ushort h = bf16rne(fs[e]);
                hv[e] = (short)h;
                lv[e] = (short)bf16rne(fs[e] - bf2f(h));
            }
            int su = uc ^ (row & 7);
            *(bf16x8*)(xhi + row * 128 + su * 8) = hv;
            *(bf16x8*)(xlo + row * 128 + su * 8) = lv;
        }
        __syncthreads();
        #pragma unroll
        for (int ks = 0; ks < 4; ++ks) {
            bf16x8 ah[2], al[2], bh[3], bl[3];
            #pragma unroll
            for (int ar = 0; ar < 2; ++ar) {
                int row = ar * 16 + (lane & 15);
                int su = (ks * 4 + (lane >> 4)) ^ (row & 7);
                ah[ar] = *(const bf16x8*)(xhi + row * 128 + su * 8);
                al[ar] = *(const bf16x8*)(xlo + row * 128 + su * 8);
            }
            const int koff = j0 + ks * 32 + (lane >> 4) * 8;
            #pragma unroll
            for (int bc = 0; bc < 3; ++bc) {
                int n = wid * 48 + bc * 16 + (lane & 15);
                bh[bc] = *(const bf16x8*)(Whi + (size_t)n * HH + koff);
                bl[bc] = *(const bf16x8*)(Wlo + (size_t)n * HH + koff);
            }
            #pragma unroll
            for (int ar = 0; ar < 2; ++ar)
                #pragma unroll
                for (int bc = 0; bc < 3; ++bc) {
                    acc[ar][bc] = MFMA16(ah[ar], bh[bc], acc[ar][bc]);
                    acc[ar][bc] = MFMA16(ah[ar], bl[bc], acc[ar][bc]);
                    acc[ar][bc] = MFMA16(al[ar], bh[bc], acc[ar][bc]);
                }
        }
    }
    __syncthreads();
    #pragma unroll
    for (int ar = 0; ar < 2; ++ar)
        #pragma unroll
        for (int bc = 0; bc < 3; ++bc) {
            int n = wid * 48 + bc * 16 + (lane & 15);
            #pragma unroll
            for (int r = 0; r < 4; ++r) {
                int row = ar * 16 + (lane >> 4) * 4 + r;
                ctile[row * 193 + n] = acc[ar][bc][r];
            }
        }
    __syncthreads();
    if (t < 96) {
        int mat = t >> 5, row = t & 31;
        float ss = 0.f;
        #pragma unroll 8
        for (int d = 0; d < 64; ++d) {
            float v = ctile[row * 193 + mat * 64 + d] + bsh[mat * 64 + d];
            ss = fmaf(v, v, ss);
        }
        rns[t] = 1.0f / fmaxf(sqrtf(ss), 1e-12f);
    }
    __syncthreads();
    #pragma unroll
    for (int i = 0; i < 24; ++i) {
        int idx = i * 256 + t;
        int row = idx / 192;
        int n = idx - row * 192;
        float v = (ctile[row * 193 + n] + bsh[n]) * rns[(n >> 6) * 32 + row];
        size_t off = (size_t)(row0 + row) * DD + (n & 63);
        if (n < 64) {
            ushort h = bf16rne(v);
            qh[off] = h; ql[off] = bf16rne(v - bf2f(h));
        } else if (n < 128) {
            ushort h = bf16rne(v);
            kh[off] = h; kl[off] = bf16rne(v - bf2f(h));
        } else {
            vw[off] = v;
        }
    }
}

// K2: colsum[b][k] = sum_q score(q,k). Recompute via split-bf16 MFMA; no score store.
// Grid = 8 b * 64 qtile(32) = 512 blocks, 256 threads. Wave w: k-range [512w, 512w+512).
__global__ __launch_bounds__(256) void k_colsum(
    const ushort* __restrict__ qh, const ushort* __restrict__ ql,
    const ushort* __restrict__ kh, const ushort* __restrict__ kl,
    float* __restrict__ colsum)
{
    __shared__ float cls[SS];
    const int t = threadIdx.x;
    const int lane = t & 63;
    const int w = t >> 6;
    const int b = blockIdx.x >> 6;
    const int q0 = (blockIdx.x & 63) * 32;
    #pragma unroll
    for (int i = 0; i < 8; ++i) cls[t + i * 256] = 0.f;

    bf16x8 ah[2][2], al[2][2];
    #pragma unroll
    for (int rt = 0; rt < 2; ++rt)
        #pragma unroll
        for (int ks = 0; ks < 2; ++ks) {
            size_t off = (size_t)(b * SS + q0 + rt * 16 + (lane & 15)) * DD + ks * 32 + (lane >> 4) * 8;
            ah[rt][ks] = *(const bf16x8*)(qh + off);
            al[rt][ks] = *(const bf16x8*)(ql + off);
        }
    __syncthreads();
    const int kb = w * 512;
    #pragma unroll 2
    for (int kt = 0; kt < 32; ++kt) {
        size_t roff = (size_t)(b * SS + kb + kt * 16 + (lane & 15)) * DD + (lane >> 4) * 8;
        bf16x8 bh0 = *(const bf16x8*)(kh + roff);
        bf16x8 bl0 = *(const bf16x8*)(kl + roff);
        bf16x8 bh1 = *(const bf16x8*)(kh + roff + 32);
        bf16x8 bl1 = *(const bf16x8*)(kl + roff + 32);
        f32x4 a0 = (f32x4){0.f, 0.f, 0.f, 0.f};
        f32x4 a1 = (f32x4){0.f, 0.f, 0.f, 0.f};
        a0 = MFMA16(ah[0][0], bh0, a0); a0 = MFMA16(ah[0][1], bh1, a0);
        a1 = MFMA16(ah[1][0], bh0, a1); a1 = MFMA16(ah[1][1], bh1, a1);
        a0 = MFMA16(ah[0][0], bl0, a0); a0 = MFMA16(ah[0][1], bl1, a0);
        a1 = MFMA16(ah[1][0], bl0, a1); a1 = MFMA16(ah[1][1], bl1, a1);
        a0 = MFMA16(al[0][0], bh0, a0); a0 = MFMA16(al[0][1], bh1, a0);
        a1 = MFMA16(al[1][0], bh0, a1); a1 = MFMA16(al[1][1], bh1, a1);
        float s = 0.f;
        #pragma unroll
        for (int r = 0; r < 4; ++r) {
            s += score_fn(a0[r]);
            s += score_fn(a1[r]);
        }
        s += __shfl_xor(s, 16, 64);
        s += __shfl_xor(s, 32, 64);
        if (lane < 16) cls[kb + kt * 16 + lane] += s;
    }
    __syncthreads();
    #pragma unroll
    for (int i = 0; i < 8; ++i)
        atomicAdd(&colsum[b * SS + t + i * 256], cls[t + i * 256]);
}

// K3: c = colsum^-0.5; cvT[b][j][k] = bf16(c*v[k][j]) for j<64, row 64 = bf16(c).
__global__ __launch_bounds__(256) void k_cvc(
    const float* __restrict__ vw, const float* __restrict__ colsum,
    ushort* __restrict__ cvT)
{
    __shared__ float vs[128][68];
    const int t = threadIdx.x;
    const int b = blockIdx.x >> 4;
    const int k0 = (blockIdx.x & 15) * 128;
    #pragma unroll
    for (int i = 0; i < 8; ++i) {
        int idx = i * 256 + t;
        int r = idx >> 4, c4 = idx & 15;
        float4 v4 = *(const float4*)&vw[(size_t)(b * SS + k0 + r) * DD + c4 * 4];
        *(float4*)&vs[r][c4 * 4] = v4;
    }
    __syncthreads();
    const int tk = t & 127;
    const int tj = t >> 7;
    float c = 1.0f / sqrtf(colsum[b * SS + k0 + tk]);
    #pragma unroll
    for (int jj = 0; jj < 32; ++jj) {
        int j = jj * 2 + tj;
        cvT[((size_t)b * NCV + j) * SS + k0 + tk] = bf16rne(c * vs[tk][j]);
    }
    if (tj == 0) cvT[((size_t)b * NCV + 64) * SS + k0 + tk] = bf16rne(c);
}

// K4: per 16 q-rows: recompute score -> bf16 LDS tile (swizzled), D via VALU+shfl,
// N = scT @ cvT via MFMA, out = N/D, probs = s*c/D streamed from LDS.
__global__ __launch_bounds__(256) void k_final(
    const ushort* __restrict__ qh, const ushort* __restrict__ ql,
    const ushort* __restrict__ kh, const ushort* __restrict__ kl,
    const ushort* __restrict__ cvT,
    float* __restrict__ probs, float* __restrict__ out)
{
    __shared__ ushort scT[16 * SS];    // 64 KB, [q][k] bf16, byte ^= (q&7)<<4
    __shared__ float dPart[4][16];
    __shared__ float dInv[16];
    const int t = threadIdx.x;
    const int lane = t & 63;
    const int w = t >> 6;
    const int b = blockIdx.x >> 7;
    const int q0 = (blockIdx.x & 127) * 16;

    bf16x8 ah[2], al[2];
    #pragma unroll
    for (int ks = 0; ks < 2; ++ks) {
        size_t off = (size_t)(b * SS + q0 + (lane & 15)) * DD + ks * 32 + (lane >> 4) * 8;
        ah[ks] = *(const bf16x8*)(qh + off);
        al[ks] = *(const bf16x8*)(ql + off);
    }
    const ushort* cbrow = cvT + ((size_t)b * NCV + 64) * SS;
    const int kb = w * 512;
    float dacc[4] = {0.f, 0.f, 0.f, 0.f};

    // Phase A: score tiles for k in [kb, kb+512)
    #pragma unroll 2
    for (int kt = 0; kt < 32; ++kt) {
        const int kk = kb + kt * 16 + (lane & 15);
        size_t roff = (size_t)(b * SS + kk) * DD + (lane >> 4) * 8;
        bf16x8 bh0 = *(const bf16x8*)(kh + roff);
        bf16x8 bl0 = *(const bf16x8*)(kl + roff);
        bf16x8 bh1 = *(const bf16x8*)(kh + roff + 32);
        bf16x8 bl1 = *(const bf16x8*)(kl + roff + 32);
        f32x4 a = (f32x4){0.f, 0.f, 0.f, 0.f};
        a = MFMA16(ah[0], bh0, a); a = MFMA16(ah[1], bh1, a);
        a = MFMA16(ah[0], bl0, a); a = MFMA16(ah[1], bl1, a);
        a = MFMA16(al[0], bh0, a); a = MFMA16(al[1], bh1, a);
        float cb = bf2f(cbrow[kk]);
        const int kx2 = kk * 2;
        #pragma unroll
        for (int r = 0; r < 4; ++r) {
            int q = (lane >> 4) * 4 + r;
            float s = score_fn(a[r]);
            ushort sb = bf16rne(s);
            *(ushort*)((char*)scT + q * 4096 + (kx2 ^ ((q & 7) << 4))) = sb;
            dacc[r] = fmaf(bf2f(sb), cb, dacc[r]);
        }
    }
    #pragma unroll
    for (int r = 0; r < 4; ++r) {
        float d = dacc[r];
        d += __shfl_xor(d, 1, 64);
        d += __shfl_xor(d, 2, 64);
        d += __shfl_xor(d, 4, 64);
        d += __shfl_xor(d, 8, 64);
        if ((lane & 15) == 0) dPart[w][(lane >> 4) * 4 + r] = d;
    }
    __syncthreads();
    if (t < 16) dInv[t] = 1.0f / (dPart[0][t] + dPart[1][t] + dPart[2][t] + dPart[3][t]);
    __syncthreads();

    // Phase B: N = scT @ cvT, wave w owns output cols [16w, 16w+16)
    {
        const int col = w * 16 + (lane & 15);
        const int q = lane & 15;
        const int xorv = (q & 7) << 4;
        const size_t cvbase = ((size_t)b * NCV + col) * SS;
        f32x4 n0 = (f32x4){0.f, 0.f, 0.f, 0.f};
        f32x4 n1 = (f32x4){0.f, 0.f, 0.f, 0.f};
        #pragma unroll 4
        for (int kstep = 0; kstep < 64; kstep += 2) {
            int k2a = kstep * 64 + (lane >> 4) * 16;
            bf16x8 af0 = *(bf16x8*)((char*)scT + q * 4096 + (k2a ^ xorv));
            bf16x8 bf0 = *(const bf16x8*)(cvT + cvbase + kstep * 32 + (lane >> 4) * 8);
            n0 = MFMA16(af0, bf0, n0);
            bf16x8 af1 = *(bf16x8*)((char*)scT + q * 4096 + ((k2a + 64) ^ xorv));
            bf16x8 bf1 = *(const bf16x8*)(cvT + cvbase + (kstep + 1) * 32 + (lane >> 4) * 8);
            n1 = MFMA16(af1, bf1, n1);
        }
        #pragma unroll
        for (int r = 0; r < 4; ++r) {
            int qq = (lane >> 4) * 4 + r;
            out[(size_t)(b * SS + q0 + qq) * DD + col] = (n0[r] + n1[r]) * dInv[qq];
        }
    }

    // Phase C: probs = s * c / D, wave w owns rows [4w, 4w+4)
    #pragma unroll
    for (int rr = 0; rr < 4; ++rr) {
        const int q = w * 4 + rr;
        const float di = dInv[q];
        const int xorv = (q & 7) << 4;
        const size_t prow = (size_t)(b * SS + q0 + q) * SS;
        #pragma unroll
        for (int i = 0; i < 4; ++i) {
            int k = i * 512 + lane * 8;
            bf16x8 sv = *(bf16x8*)((char*)scT + q * 4096 + ((k * 2) ^ xorv));
            bf16x8 cv8 = *(const bf16x8*)(cbrow + k);
            float4 o0, o1;
            o0.x = bf2f((ushort)sv[0]) * bf2f((ushort)cv8[0]) * di;
            o0.y = bf2f((ushort)sv[1]) * bf2f((ushort)cv8[1]) * di;
            o0.z = bf2f((ushort)sv[2]) * bf2f((ushort)cv8[2]) * di;
            o0.w = bf2f((ushort)sv[3]) * bf2f((ushort)cv8[3]) * di;
            o1.x = bf2f((ushort)sv[4]) * bf2f((ushort)cv8[4]) * di;
            o1.y = bf2f((ushort)sv[5]) * bf2f((ushort)cv8[5]) * di;
            o1.z = bf2f((ushort)sv[6]) * bf2f((ushort)cv8[6]) * di;
            o1.w = bf2f((ushort)sv[7]) * bf2f((ushort)cv8[7]) * di;
            *(float4*)&probs[prow + k] = o0;
            *(float4*)&probs[prow + k + 4] = o1;
        }
    }
}

extern "C" void kernel_launch(void* const* d_in, const int* in_sizes, int n_in,
                              void* d_out, int out_size, void* d_ws, size_t ws_size,
                              hipStream_t stream)
{
    const float* x  = (const float*)d_in[0];
    const float* Wq = (const float*)d_in[1];
    const float* bq = (const float*)d_in[2];
    const float* Wk = (const float*)d_in[3];
    const float* bk = (const float*)d_in[4];
    const float* Wv = (const float*)d_in[5];
    const float* bv = (const float*)d_in[6];

    float* out   = (float*)d_out;                       // [8,2048,64]
    float* probs = out + (size_t)BB * SS * DD;          // [8,2048,2048]

    const size_t NQ = (size_t)BB * SS * DD;             // 1,048,576
    ushort* qh    = (ushort*)d_ws;
    ushort* ql    = qh + NQ;
    ushort* kh    = ql + NQ;
    ushort* kl    = kh + NQ;
    float*  vw    = (float*)(kl + NQ);
    float*  colsum = vw + NQ;
    ushort* cvT   = (ushort*)(colsum + BB * SS);
    ushort* Whi   = cvT + (size_t)BB * NCV * SS;
    ushort* Wlo   = Whi + (size_t)192 * HH;
    float*  bcat  = (float*)(Wlo + (size_t)192 * HH);

    hipMemsetAsync(colsum, 0, BB * SS * sizeof(float), stream);
    k_prep  <<<192, 256, 0, stream>>>(Wq, Wk, Wv, bq, bk, bv, Whi, Wlo, bcat);
    k_projmm<<<512, 256, 0, stream>>>(x, Whi, Wlo, bcat, qh, ql, kh, kl, vw);
    k_colsum<<<512, 256, 0, stream>>>(qh, ql, kh, kl, colsum);
    k_cvc   <<<128, 256, 0, stream>>>(vw, colsum, cvT);
    k_final <<<1024, 256, 0, stream>>>(qh, ql, kh, kl, cvT, probs, out);
}